// Round 4
// baseline (161.942 us; speedup 1.0000x reference)
//
#include <hip/hip_runtime.h>
#include <math.h>

#define N_TOK 40
#define N1    41      // N_TOK + 1
#define BS    8
#define DD    256     // D
#define HH    256     // H
#define NTRI  10660   // C(41,3)
#define NPAIR 780     // pairs (i,k) with k-i>=2
#define ROWF  (BS * N1 * HH)  // 83968 floats per [b][t][h] array
#define MNEG  (-1e38f)
#define DPB   256
#define GPB   49      // blocks per batch group
#define NBF   (BS * GPB)   // 392 blocks
#define NPROJ 164     // proj roles: 41 t * 4 h-quarters

// ---- persistent sync state (module .bss: zero at load) ----
// g_proj / g_sctr reset at END of launch by last DP arrival (epoch via
// monotonic g_fin % 8). Kernel-end flush + stream ordering make resets
// visible to the next launch.
__device__ unsigned long long g_proj;          // proj arrivals (164/launch)
__device__ unsigned long long g_sctr[BS * 16]; // per-b score arrivals, 128B stride
__device__ unsigned long long g_fin;           // monotonic, never reset

// ---------------- DP helpers (verbatim) ----------------
__device__ __forceinline__ int tri_base(int i) { return (i * (81 - i)) >> 1; }
#define BIDX(i, j) (tri_base(i) + ((j) - (i) - 1))

constexpr int soff(int W) {
    int s = 0;
    for (int v = 2; v < W; ++v) s += (N1 - v) * (v - 1);
    return s;
}
constexpr int pick_T(int m, int nj) {
    int T = 1;
    while (T < 16 && m * (T * 2) <= DPB && T < nj) T *= 2;
    return T;
}

template<int W>
__device__ __forceinline__ void dp_step(float* __restrict__ Btri,
                                        const float* __restrict__ Sl, int tid)
{
    constexpr int m    = N1 - W;
    constexpr int nj   = W - 1;
    constexpr int T    = pick_T(m, nj);
    constexpr int CH   = (nj + T - 1) / T;
    constexpr int base = soff(W);

    if (tid < m * T) {
        const int i = tid / T;
        const int h = tid % T;
        const int k = i + W;

        float g[CH];
        #pragma unroll
        for (int q = 0; q < CH; ++q) {
            int jp = h + q * T;
            bool live = (q < CH - 1) || (jp < nj);
            int jj = live ? jp : 0;
            float v = Sl[base + i * nj + jj]
                    + Btri[BIDX(i, i + 1 + jj)]
                    + Btri[BIDX(i + 1 + jj, k)];
            g[q] = live ? v : MNEG;
        }
        float mx = g[0];
        #pragma unroll
        for (int q = 1; q < CH; ++q) mx = fmaxf(mx, g[q]);
        float s = 0.f;
        #pragma unroll
        for (int q = 0; q < CH; ++q) s += __expf(g[q] - mx);
        #pragma unroll
        for (int d = 1; d < T; d <<= 1) {
            float mo = __shfl_xor(mx, d);
            float so = __shfl_xor(s, d);
            float nm = fmaxf(mx, mo);
            s = s * __expf(mx - nm) + so * __expf(mo - nm);
            mx = nm;
        }
        if (h == 0)
            Btri[BIDX(i, k)] = mx + __logf(s);
    }
    __syncthreads();
}

template<int W>
__device__ __forceinline__ void dp_from(float* __restrict__ Btri,
                                        const float* __restrict__ Sl, int tid)
{
    dp_step<W>(Btri, Sl, tid);
    if constexpr (W + 1 <= N_TOK) dp_from<W + 1>(Btri, Sl, tid);
}

// ---------------- Fused: proj(164 scattered roles) -> [flag] -> score -> [per-b] -> dp
__global__ __launch_bounds__(256) void k_fused(
    const float* __restrict__ enc, const float* __restrict__ W1,
    const float* __restrict__ b1v, const float* __restrict__ W2,
    const float* __restrict__ b2,  const int* __restrict__ lengths,
    float* __restrict__ P, float* __restrict__ Qb, float* __restrict__ Dd,
    float* __restrict__ S, float* __restrict__ out)
{
    const int tid = threadIdx.x;
    const int blk = blockIdx.x;
    const int b   = blk / GPB;        // batch group
    const int g   = blk - b * GPB;    // block index within group

    __shared__ __align__(16) union SH {
        float e[BS][DD];                                  // proj: 8 KB
        struct { float Sl[NTRI]; float Btri[820]; } dp;   // dp: 45920 B
    } sh;

    // ======== phase 1: projection quarter-roles, scattered across groups.
    // pid = g*8 + b for g<=20 (pid<164): t = pid>>2, h-quarter = pid&3.
    // Thread = one h (64 per block) x two b's; per-(b,t,h) fmaf chain over
    // ascending d is verbatim -> P/Qb/Dd bitwise identical.
    const int pid = g * 8 + b;
    if (g <= 20 && pid < NPROJ) {
        const int t  = pid >> 2;
        const int q4 = pid & 3;
        const int h  = q4 * 64 + (tid & 63);
        const int bp = tid >> 6;          // 0..3
        const int bA = bp * 2, bB = bp * 2 + 1;

        #pragma unroll
        for (int r = 0; r < BS; ++r)
            sh.e[r][tid] = enc[(t * BS + r) * DD + tid];
        __syncthreads();

        float a0 = 0.f, c0 = 0.f, a1 = 0.f, c1 = 0.f;
        for (int d = 0; d < DD; ++d) {
            float wp = W1[d * HH + h];
            float wq = W1[(DD + d) * HH + h];
            float e0 = sh.e[bA][d];
            float e1 = sh.e[bB][d];
            a0 = fmaf(e0, wp, a0); c0 = fmaf(e0, wq, c0);
            a1 = fmaf(e1, wp, a1); c1 = fmaf(e1, wq, c1);
        }
        float bv = b1v[h];
        int iA = ((bA * N1) + t) * HH + h;
        int iB = ((bB * N1) + t) * HH + h;
        P[iA]  = a0;           P[iB]  = a1;
        Qb[iA] = c0 + bv;      Qb[iB] = c1 + bv;
        Dd[iA] = a0 - c0;      Dd[iB] = a1 - c1;

        __syncthreads();
        if (tid == 0) {
            __threadfence();
            __hip_atomic_fetch_add(&g_proj, 1ull, __ATOMIC_RELEASE,
                                   __HIP_MEMORY_SCOPE_AGENT);
        }
    }

    // ---- barrier 1: wait for 164 proj arrivals (relaxed polls + backoff)
    if (tid == 0) {
        while (__hip_atomic_load(&g_proj, __ATOMIC_RELAXED,
                                 __HIP_MEMORY_SCOPE_AGENT) < (unsigned long long)NPROJ)
            __builtin_amdgcn_s_sleep(8);
        __threadfence();   // acquire before reading P/Qb/Dd
    }
    __syncthreads();

    // ======== phase 2: scores — group g covers pairs of batch b (verbatim)
    {
        const int lg = g * 256 + tid;
        const int p  = lg >> 4;          // pair index, w-descending
        const int t  = lg & 15;

        if (p < NPAIR) {
            int c = (int)((sqrtf(8.f * (float)p + 1.f) - 1.f) * 0.5f);
            while ((c + 1) * (c + 2) / 2 <= p) ++c;
            while (c * (c + 1) / 2 > p) --c;
            const int w    = 40 - c;
            const int i    = p - c * (c + 1) / 2;
            const int k    = i + w;
            const int nj   = w - 1;
            const int n2   = w - 2;
            const int base = n2 * (n2 + 1) * (119 - 2 * n2) / 6;   // == soff(w)

            const float4* Pr  = (const float4*)(P  + ((b * N1 + i) << 8)) + t * 4;
            const float4* Qr  = (const float4*)(Qb + ((b * N1 + k) << 8)) + t * 4;
            const float4* W2r = (const float4*)(W2) + t * 8;

            float4 pp[4], qq[4], wa[4], wb[4];
            #pragma unroll
            for (int q = 0; q < 4; ++q) {
                pp[q] = Pr[q]; qq[q] = Qr[q];
                wa[q] = W2r[q * 2]; wb[q] = W2r[q * 2 + 1];
            }
            const float bb0 = b2[0], bb1 = b2[1];

            const float4* Drow = (const float4*)(Dd + ((b * N1 + i + 1) << 8)) + t * 4;
            float* Sout = S + b * NTRI + base + i * nj;

            for (int jp = 0; jp < nj; ++jp) {
                float s0 = 0.f, s1 = 0.f;
                #pragma unroll
                for (int q = 0; q < 4; ++q) {
                    float4 dd = Drow[q];
                    float r0 = fmaxf(dd.x + qq[q].x - pp[q].x, 0.f);
                    float r1 = fmaxf(dd.y + qq[q].y - pp[q].y, 0.f);
                    float r2 = fmaxf(dd.z + qq[q].z - pp[q].z, 0.f);
                    float r3 = fmaxf(dd.w + qq[q].w - pp[q].w, 0.f);
                    s0 = fmaf(r0, wa[q].x, s0); s1 = fmaf(r0, wa[q].y, s1);
                    s0 = fmaf(r1, wa[q].z, s0); s1 = fmaf(r1, wa[q].w, s1);
                    s0 = fmaf(r2, wb[q].x, s0); s1 = fmaf(r2, wb[q].y, s1);
                    s0 = fmaf(r3, wb[q].z, s0); s1 = fmaf(r3, wb[q].w, s1);
                }
                #pragma unroll
                for (int d = 1; d < 16; d <<= 1) {
                    s0 += __shfl_xor(s0, d);
                    s1 += __shfl_xor(s1, d);
                }
                if (t == 0) {
                    float S0 = s0 + bb0, S1 = s1 + bb1;
                    Sout[jp] = fmaxf(S0, S1) + log1pf(__expf(-fabsf(S0 - S1)));
                }
                Drow += 64;
            }
        }
    }

    // ---- per-b arrival: 49 RMWs per counter, 8 counters in parallel
    __syncthreads();
    if (tid == 0) {
        __threadfence();
        __hip_atomic_fetch_add(&g_sctr[b * 16], 1ull, __ATOMIC_RELEASE,
                               __HIP_MEMORY_SCOPE_AGENT);
    }
    // DP role: LAST block of each group — never a proj block (g=48>20),
    // lightest score pairs (p>=768, nj<=2). All others exit now.
    if (g != GPB - 1) return;

    if (tid == 0) {
        while (__hip_atomic_load(&g_sctr[b * 16], __ATOMIC_RELAXED,
                                 __HIP_MEMORY_SCOPE_AGENT) < (unsigned long long)GPB)
            __builtin_amdgcn_s_sleep(8);
        __threadfence();
    }
    __syncthreads();

    // ======== phase 3: DP for batch b (verbatim)
    {
        const float4* src = (const float4*)(S + b * NTRI);
        float4* dst = (float4*)sh.dp.Sl;
        for (int x = tid; x < NTRI / 4; x += DPB) dst[x] = src[x];
        if (tid < N_TOK) sh.dp.Btri[tri_base(tid)] = 0.f;
        __syncthreads();

        dp_from<2>(sh.dp.Btri, sh.dp.Sl, tid);

        if (tid == 0) {
            int L = lengths[b];
            out[b] = sh.dp.Btri[BIDX(0, L)];
        }
    }

    // ---- end-of-launch reset (8th DP arrival, epoch via monotonic g_fin)
    if (tid == 0) {
        __threadfence();
        unsigned long long t = __hip_atomic_fetch_add(
            &g_fin, 1ull, __ATOMIC_ACQ_REL, __HIP_MEMORY_SCOPE_AGENT);
        if ((t & 7ull) == 7ull) {
            __hip_atomic_store(&g_proj, 0ull, __ATOMIC_RELAXED,
                               __HIP_MEMORY_SCOPE_AGENT);
            #pragma unroll
            for (int bb_ = 0; bb_ < BS; ++bb_)
                __hip_atomic_store(&g_sctr[bb_ * 16], 0ull, __ATOMIC_RELAXED,
                                   __HIP_MEMORY_SCOPE_AGENT);
        }
    }
}

extern "C" void kernel_launch(void* const* d_in, const int* in_sizes, int n_in,
                              void* d_out, int out_size, void* d_ws, size_t ws_size,
                              hipStream_t stream)
{
    const float* enc = (const float*)d_in[0];
    const float* W1  = (const float*)d_in[1];
    const float* b1  = (const float*)d_in[2];
    const float* W2  = (const float*)d_in[3];
    const float* b2  = (const float*)d_in[4];
    const int* lengths = (const int*)d_in[5];

    float* ws = (float*)d_ws;
    float* P  = ws;
    float* Qb = ws + ROWF;
    float* Dd = ws + 2 * ROWF;
    float* S  = ws + 3 * ROWF;

    k_fused<<<dim3(NBF), dim3(256), 0, stream>>>(
        enc, W1, b1, W2, b2, lengths, P, Qb, Dd, S, (float*)d_out);
}

// Round 5
// 150.320 us; speedup vs baseline: 1.0773x; 1.0773x over previous
//
#include <hip/hip_runtime.h>
#include <math.h>

#define N_TOK 40
#define N1    41      // N_TOK + 1
#define BS    8
#define DD    256     // D
#define HH    256     // H
#define NTRI  10660   // C(41,3)
#define NPAIR 780     // pairs (i,k) with k-i>=2
#define ROWF  (BS * N1 * HH)  // 83968 floats per [b][t][h] array
#define MNEG  (-1e38f)
#define DPB   256
#define GPB   49      // blocks per batch group
#define NBF   (BS * GPB)   // 392 blocks
#define NPB   11      // proj blocks per group: ceil(41 rows / 4 rows-per-block)

// ---- persistent sync state (module .bss: zero at load) ----
// Per-group sync lines, 4 KB apart (different channels), two counters per
// group 512 B apart: [b][0] = proj arrivals (NPB), [b][64] = score arrivals
// (GPB). Each group's DP block is the LAST user of its group's counters and
// resets them before exiting; kernel-end flush + stream ordering make the
// reset visible to the next launch / graph replay.
__device__ unsigned long long g_sync[BS][512];

// ---------------- DP helpers (verbatim) ----------------
__device__ __forceinline__ int tri_base(int i) { return (i * (81 - i)) >> 1; }
#define BIDX(i, j) (tri_base(i) + ((j) - (i) - 1))

constexpr int soff(int W) {
    int s = 0;
    for (int v = 2; v < W; ++v) s += (N1 - v) * (v - 1);
    return s;
}
constexpr int pick_T(int m, int nj) {
    int T = 1;
    while (T < 16 && m * (T * 2) <= DPB && T < nj) T *= 2;
    return T;
}

template<int W>
__device__ __forceinline__ void dp_step(float* __restrict__ Btri,
                                        const float* __restrict__ Sl, int tid)
{
    constexpr int m    = N1 - W;
    constexpr int nj   = W - 1;
    constexpr int T    = pick_T(m, nj);
    constexpr int CH   = (nj + T - 1) / T;
    constexpr int base = soff(W);

    if (tid < m * T) {
        const int i = tid / T;
        const int h = tid % T;
        const int k = i + W;

        float g[CH];
        #pragma unroll
        for (int q = 0; q < CH; ++q) {
            int jp = h + q * T;
            bool live = (q < CH - 1) || (jp < nj);
            int jj = live ? jp : 0;
            float v = Sl[base + i * nj + jj]
                    + Btri[BIDX(i, i + 1 + jj)]
                    + Btri[BIDX(i + 1 + jj, k)];
            g[q] = live ? v : MNEG;
        }
        float mx = g[0];
        #pragma unroll
        for (int q = 1; q < CH; ++q) mx = fmaxf(mx, g[q]);
        float s = 0.f;
        #pragma unroll
        for (int q = 0; q < CH; ++q) s += __expf(g[q] - mx);
        #pragma unroll
        for (int d = 1; d < T; d <<= 1) {
            float mo = __shfl_xor(mx, d);
            float so = __shfl_xor(s, d);
            float nm = fmaxf(mx, mo);
            s = s * __expf(mx - nm) + so * __expf(mo - nm);
            mx = nm;
        }
        if (h == 0)
            Btri[BIDX(i, k)] = mx + __logf(s);
    }
    __syncthreads();
}

template<int W>
__device__ __forceinline__ void dp_from(float* __restrict__ Btri,
                                        const float* __restrict__ Sl, int tid)
{
    dp_step<W>(Btri, Sl, tid);
    if constexpr (W + 1 <= N_TOK) dp_from<W + 1>(Btri, Sl, tid);
}

// ------- Fused: per-group proj -> [per-b flag] -> score -> [per-b ctr] -> dp
__global__ __launch_bounds__(256) void k_fused(
    const float* __restrict__ enc, const float* __restrict__ W1,
    const float* __restrict__ b1v, const float* __restrict__ W2,
    const float* __restrict__ b2,  const int* __restrict__ lengths,
    float* __restrict__ P, float* __restrict__ Qb, float* __restrict__ Dd,
    float* __restrict__ S, float* __restrict__ out)
{
    const int tid = threadIdx.x;
    const int blk = blockIdx.x;
    const int b   = blk / GPB;        // batch group
    const int g   = blk - b * GPB;    // block index within group

    __shared__ __align__(16) union SH {
        float e4[4][DD];                                  // proj: 4 KB
        struct { float Sl[NTRI]; float Btri[820]; } dp;   // dp: 45920 B
    } sh;

    // ======== phase 1: proj for THIS batch only. Block g<11 covers rows
    // t = 4g..4g+3 (g=10: row 40 only). 64 lanes per row, 4 h's per lane via
    // float4 W1 column loads. Per-h ascending-d fmaf chain is verbatim ->
    // P/Qb/Dd bitwise identical to all previous rounds.
    if (g < NPB) {
        const int slot = tid >> 6;          // 0..3: row slot
        const int lane = tid & 63;
        const int t    = 4 * g + slot;
        const bool live = (t < N1);

        if (live) {
            // stage e row (b,t): 64 lanes x float4 = 256 floats
            *(float4*)&sh.e4[slot][lane << 2] =
                *(const float4*)&enc[(t * BS + b) * DD + (lane << 2)];
        }
        __syncthreads();

        if (live) {
            float4 aa = {0.f, 0.f, 0.f, 0.f};
            float4 cc = {0.f, 0.f, 0.f, 0.f};
            const int h4 = lane << 2;
            for (int d = 0; d < DD; ++d) {
                float4 wp = *(const float4*)&W1[d * HH + h4];
                float4 wq = *(const float4*)&W1[(DD + d) * HH + h4];
                float ev = sh.e4[slot][d];
                aa.x = fmaf(ev, wp.x, aa.x); cc.x = fmaf(ev, wq.x, cc.x);
                aa.y = fmaf(ev, wp.y, aa.y); cc.y = fmaf(ev, wq.y, cc.y);
                aa.z = fmaf(ev, wp.z, aa.z); cc.z = fmaf(ev, wq.z, cc.z);
                aa.w = fmaf(ev, wp.w, aa.w); cc.w = fmaf(ev, wq.w, cc.w);
            }
            float4 bv = *(const float4*)&b1v[h4];
            const int base = ((b * N1) + t) * HH + h4;
            *(float4*)&P[base] = aa;
            float4 qv = {cc.x + bv.x, cc.y + bv.y, cc.z + bv.z, cc.w + bv.w};
            *(float4*)&Qb[base] = qv;
            float4 dv = {aa.x - cc.x, aa.y - cc.y, aa.z - cc.z, aa.w - cc.w};
            *(float4*)&Dd[base] = dv;
        }
        __syncthreads();   // all waves' stores drained (barrier waitcnt)
        if (tid == 0) {
            __threadfence();
            __hip_atomic_fetch_add(&g_sync[b][0], 1ull, __ATOMIC_RELEASE,
                                   __HIP_MEMORY_SCOPE_AGENT);
        }
    }

    // ---- barrier 1 (per-group): wait for this group's NPB proj arrivals.
    // <=49 pollers per line, 8 independent lines, relaxed polls + backoff.
    if (tid == 0) {
        while (__hip_atomic_load(&g_sync[b][0], __ATOMIC_RELAXED,
                                 __HIP_MEMORY_SCOPE_AGENT) < (unsigned long long)NPB)
            __builtin_amdgcn_s_sleep(32);
        __threadfence();   // acquire before reading P/Qb/Dd
    }
    __syncthreads();

    // ======== phase 2: scores — group g covers pairs of batch b (verbatim)
    {
        const int lg = g * 256 + tid;
        const int p  = lg >> 4;          // pair index, w-descending
        const int t  = lg & 15;

        if (p < NPAIR) {
            int c = (int)((sqrtf(8.f * (float)p + 1.f) - 1.f) * 0.5f);
            while ((c + 1) * (c + 2) / 2 <= p) ++c;
            while (c * (c + 1) / 2 > p) --c;
            const int w    = 40 - c;
            const int i    = p - c * (c + 1) / 2;
            const int k    = i + w;
            const int nj   = w - 1;
            const int n2   = w - 2;
            const int base = n2 * (n2 + 1) * (119 - 2 * n2) / 6;   // == soff(w)

            const float4* Pr  = (const float4*)(P  + ((b * N1 + i) << 8)) + t * 4;
            const float4* Qr  = (const float4*)(Qb + ((b * N1 + k) << 8)) + t * 4;
            const float4* W2r = (const float4*)(W2) + t * 8;

            float4 pp[4], qq[4], wa[4], wb[4];
            #pragma unroll
            for (int q = 0; q < 4; ++q) {
                pp[q] = Pr[q]; qq[q] = Qr[q];
                wa[q] = W2r[q * 2]; wb[q] = W2r[q * 2 + 1];
            }
            const float bb0 = b2[0], bb1 = b2[1];

            const float4* Drow = (const float4*)(Dd + ((b * N1 + i + 1) << 8)) + t * 4;
            float* Sout = S + b * NTRI + base + i * nj;

            for (int jp = 0; jp < nj; ++jp) {
                float s0 = 0.f, s1 = 0.f;
                #pragma unroll
                for (int q = 0; q < 4; ++q) {
                    float4 dd = Drow[q];
                    float r0 = fmaxf(dd.x + qq[q].x - pp[q].x, 0.f);
                    float r1 = fmaxf(dd.y + qq[q].y - pp[q].y, 0.f);
                    float r2 = fmaxf(dd.z + qq[q].z - pp[q].z, 0.f);
                    float r3 = fmaxf(dd.w + qq[q].w - pp[q].w, 0.f);
                    s0 = fmaf(r0, wa[q].x, s0); s1 = fmaf(r0, wa[q].y, s1);
                    s0 = fmaf(r1, wa[q].z, s0); s1 = fmaf(r1, wa[q].w, s1);
                    s0 = fmaf(r2, wb[q].x, s0); s1 = fmaf(r2, wb[q].y, s1);
                    s0 = fmaf(r3, wb[q].z, s0); s1 = fmaf(r3, wb[q].w, s1);
                }
                #pragma unroll
                for (int d = 1; d < 16; d <<= 1) {
                    s0 += __shfl_xor(s0, d);
                    s1 += __shfl_xor(s1, d);
                }
                if (t == 0) {
                    float S0 = s0 + bb0, S1 = s1 + bb1;
                    Sout[jp] = fmaxf(S0, S1) + log1pf(__expf(-fabsf(S0 - S1)));
                }
                Drow += 64;
            }
        }
    }

    // ---- per-b score arrival: 49 RMWs per line, 8 lines in parallel
    __syncthreads();
    if (tid == 0) {
        __threadfence();
        __hip_atomic_fetch_add(&g_sync[b][64], 1ull, __ATOMIC_RELEASE,
                               __HIP_MEMORY_SCOPE_AGENT);
    }
    // DP role: last block of each group (lightest score pairs, nj<=1).
    if (g != GPB - 1) return;

    // ---- wait for this batch's 49 score arrivals (single poller per line)
    if (tid == 0) {
        while (__hip_atomic_load(&g_sync[b][64], __ATOMIC_RELAXED,
                                 __HIP_MEMORY_SCOPE_AGENT) < (unsigned long long)GPB)
            __builtin_amdgcn_s_sleep(16);
        __threadfence();
    }
    __syncthreads();

    // ======== phase 3: DP for batch b (verbatim)
    {
        const float4* src = (const float4*)(S + b * NTRI);
        float4* dst = (float4*)sh.dp.Sl;
        for (int x = tid; x < NTRI / 4; x += DPB) dst[x] = src[x];
        if (tid < N_TOK) sh.dp.Btri[tri_base(tid)] = 0.f;
        __syncthreads();

        dp_from<2>(sh.dp.Btri, sh.dp.Sl, tid);

        if (tid == 0) {
            int L = lengths[b];
            out[b] = sh.dp.Btri[BIDX(0, L)];
        }
    }

    // ---- reset this group's counters (we are their last user this launch)
    if (tid == 0) {
        __hip_atomic_store(&g_sync[b][0], 0ull, __ATOMIC_RELAXED,
                           __HIP_MEMORY_SCOPE_AGENT);
        __hip_atomic_store(&g_sync[b][64], 0ull, __ATOMIC_RELAXED,
                           __HIP_MEMORY_SCOPE_AGENT);
    }
}

extern "C" void kernel_launch(void* const* d_in, const int* in_sizes, int n_in,
                              void* d_out, int out_size, void* d_ws, size_t ws_size,
                              hipStream_t stream)
{
    const float* enc = (const float*)d_in[0];
    const float* W1  = (const float*)d_in[1];
    const float* b1  = (const float*)d_in[2];
    const float* W2  = (const float*)d_in[3];
    const float* b2  = (const float*)d_in[4];
    const int* lengths = (const int*)d_in[5];

    float* ws = (float*)d_ws;
    float* P  = ws;
    float* Qb = ws + ROWF;
    float* Dd = ws + 2 * ROWF;
    float* S  = ws + 3 * ROWF;

    k_fused<<<dim3(NBF), dim3(256), 0, stream>>>(
        enc, W1, b1, W2, b2, lengths, P, Qb, Dd, S, (float*)d_out);
}

// Round 6
// 139.764 us; speedup vs baseline: 1.1587x; 1.0755x over previous
//
#include <hip/hip_runtime.h>
#include <math.h>

#define N_TOK 40
#define N1    41      // N_TOK + 1
#define BS    8
#define DD    256     // D
#define HH    256     // H
#define NTRI  10660   // C(41,3)
#define NPAIR 780     // pairs (i,k) with k-i>=2
#define ROWF  (BS * N1 * HH)  // 83968 floats per [b][t][h] array
#define MNEG  (-1e38f)
#define DPB   256     // DP thread-mapping constant (bit-exact vs prior rounds)
#define GPB   13      // blocks per batch group
#define NBF   (BS * GPB)   // 104 blocks
#define THR   1024    // threads per block (16 waves)
#define SCB   12      // score blocks per group; block 12 = DP block
#define QMAX  65      // pairs per score block: 65 * 12 = 780

// ---- persistent sync state (module .bss: zero at load) ----
// Per-group lines 4 KB apart: [b][0] = proj arrivals (13), [b][64] = score
// arrivals (12). The group's DP block is the last user of its two counters
// and resets them before exit; kernel-end flush + stream ordering make the
// resets visible to the next launch / graph replay.
__device__ unsigned long long g_sync[BS][512];

// ---------------- DP helpers (verbatim) ----------------
__device__ __forceinline__ int tri_base(int i) { return (i * (81 - i)) >> 1; }
#define BIDX(i, j) (tri_base(i) + ((j) - (i) - 1))

constexpr int soff(int W) {
    int s = 0;
    for (int v = 2; v < W; ++v) s += (N1 - v) * (v - 1);
    return s;
}
constexpr int pick_T(int m, int nj) {
    int T = 1;
    while (T < 16 && m * (T * 2) <= DPB && T < nj) T *= 2;
    return T;
}

template<int W>
__device__ __forceinline__ void dp_step(float* __restrict__ Btri,
                                        const float* __restrict__ Sl, int tid)
{
    constexpr int m    = N1 - W;
    constexpr int nj   = W - 1;
    constexpr int T    = pick_T(m, nj);
    constexpr int CH   = (nj + T - 1) / T;
    constexpr int base = soff(W);

    if (tid < m * T) {
        const int i = tid / T;
        const int h = tid % T;
        const int k = i + W;

        float g[CH];
        #pragma unroll
        for (int q = 0; q < CH; ++q) {
            int jp = h + q * T;
            bool live = (q < CH - 1) || (jp < nj);
            int jj = live ? jp : 0;
            float v = Sl[base + i * nj + jj]
                    + Btri[BIDX(i, i + 1 + jj)]
                    + Btri[BIDX(i + 1 + jj, k)];
            g[q] = live ? v : MNEG;
        }
        float mx = g[0];
        #pragma unroll
        for (int q = 1; q < CH; ++q) mx = fmaxf(mx, g[q]);
        float s = 0.f;
        #pragma unroll
        for (int q = 0; q < CH; ++q) s += __expf(g[q] - mx);
        #pragma unroll
        for (int d = 1; d < T; d <<= 1) {
            float mo = __shfl_xor(mx, d);
            float so = __shfl_xor(s, d);
            float nm = fmaxf(mx, mo);
            s = s * __expf(mx - nm) + so * __expf(mo - nm);
            mx = nm;
        }
        if (h == 0)
            Btri[BIDX(i, k)] = mx + __logf(s);
    }
    __syncthreads();
}

template<int W>
__device__ __forceinline__ void dp_from(float* __restrict__ Btri,
                                        const float* __restrict__ Sl, int tid)
{
    dp_step<W>(Btri, Sl, tid);
    if constexpr (W + 1 <= N_TOK) dp_from<W + 1>(Btri, Sl, tid);
}

// ------- Fused, 104 x 1024: proj(spread) -> [per-b flag] -> score(mod-12
// balanced interleave, blocks 0..11) -> [per-b ctr] -> dp (block 12)
__global__ __launch_bounds__(THR) void k_fused(
    const float* __restrict__ enc, const float* __restrict__ W1,
    const float* __restrict__ b1v, const float* __restrict__ W2,
    const float* __restrict__ b2,  const int* __restrict__ lengths,
    float* __restrict__ P, float* __restrict__ Qb, float* __restrict__ Dd,
    float* __restrict__ S, float* __restrict__ out)
{
    const int tid = threadIdx.x;
    const int blk = blockIdx.x;
    const int b   = blk / GPB;        // batch group
    const int g   = blk - b * GPB;    // block index within group (0..12)

    __shared__ __align__(16) union SH {
        float e4[5][DD];                                  // proj: 5 KB
        struct { float Sl[NTRI]; float Btri[820]; } dp;   // dp: 45920 B
    } sh;

    // ======== phase 1: proj rows for THIS batch, spread across the group.
    // Blocks 0..11: rows t = 3g..3g+2 (slots 0..2). Block 12: rows 36..40
    // (slots 0..4). 64 lanes per row, 4 h per lane via float4 W1 columns.
    // Per-(b,t,h) ascending-d fmaf chain is verbatim -> bits identical.
    {
        const int slot = tid >> 6;          // 0..15
        const int lane = tid & 63;
        const bool live = (g < SCB) ? (slot < 3) : (slot < 5);
        const int t = (g < SCB) ? (3 * g + slot) : (36 + slot);

        if (live) {
            *(float4*)&sh.e4[slot][lane << 2] =
                *(const float4*)&enc[(t * BS + b) * DD + (lane << 2)];
        }
        __syncthreads();

        if (live) {
            float4 aa = {0.f, 0.f, 0.f, 0.f};
            float4 cc = {0.f, 0.f, 0.f, 0.f};
            const int h4 = lane << 2;
            for (int d = 0; d < DD; ++d) {
                float4 wp = *(const float4*)&W1[d * HH + h4];
                float4 wq = *(const float4*)&W1[(DD + d) * HH + h4];
                float ev = sh.e4[slot][d];
                aa.x = fmaf(ev, wp.x, aa.x); cc.x = fmaf(ev, wq.x, cc.x);
                aa.y = fmaf(ev, wp.y, aa.y); cc.y = fmaf(ev, wq.y, cc.y);
                aa.z = fmaf(ev, wp.z, aa.z); cc.z = fmaf(ev, wq.z, cc.z);
                aa.w = fmaf(ev, wp.w, aa.w); cc.w = fmaf(ev, wq.w, cc.w);
            }
            float4 bv = *(const float4*)&b1v[h4];
            const int base = ((b * N1) + t) * HH + h4;
            *(float4*)&P[base] = aa;
            float4 qv = {cc.x + bv.x, cc.y + bv.y, cc.z + bv.z, cc.w + bv.w};
            *(float4*)&Qb[base] = qv;
            float4 dv = {aa.x - cc.x, aa.y - cc.y, aa.z - cc.z, aa.w - cc.w};
            *(float4*)&Dd[base] = dv;
        }
        __syncthreads();
        if (tid == 0) {
            __threadfence();
            __hip_atomic_fetch_add(&g_sync[b][0], 1ull, __ATOMIC_RELEASE,
                                   __HIP_MEMORY_SCOPE_AGENT);
        }
    }

    // ---- barrier 1 (per-group): wait for this group's 13 proj arrivals.
    if (tid == 0) {
        while (__hip_atomic_load(&g_sync[b][0], __ATOMIC_RELAXED,
                                 __HIP_MEMORY_SCOPE_AGENT) < (unsigned long long)GPB)
            __builtin_amdgcn_s_sleep(16);
        __threadfence();   // acquire before reading P/Qb/Dd
    }
    __syncthreads();

    if (g < SCB) {
        // ======== phase 2: score — block g takes pairs p = q*12+g, q=0..64
        // (mod-12 interleave of the w-descending list: balanced load, adjacent
        // groups get adjacent nj). Per-pair arithmetic & S layout verbatim.
        const int grp = tid >> 4;
        const int t   = tid & 15;

        for (int q = grp; q < QMAX; q += 64) {
            const int p = q * 12 + g;
            // p < 780 guaranteed: q<=64 -> p <= 768+11 = 779
            int c = (int)((sqrtf(8.f * (float)p + 1.f) - 1.f) * 0.5f);
            while ((c + 1) * (c + 2) / 2 <= p) ++c;
            while (c * (c + 1) / 2 > p) --c;
            const int w    = 40 - c;
            const int i    = p - c * (c + 1) / 2;
            const int k    = i + w;
            const int nj   = w - 1;
            const int n2   = w - 2;
            const int base = n2 * (n2 + 1) * (119 - 2 * n2) / 6;   // == soff(w)

            const float4* Pr  = (const float4*)(P  + ((b * N1 + i) << 8)) + t * 4;
            const float4* Qr  = (const float4*)(Qb + ((b * N1 + k) << 8)) + t * 4;
            const float4* W2r = (const float4*)(W2) + t * 8;

            float4 pp[4], qq[4], wa[4], wb[4];
            #pragma unroll
            for (int qi = 0; qi < 4; ++qi) {
                pp[qi] = Pr[qi]; qq[qi] = Qr[qi];
                wa[qi] = W2r[qi * 2]; wb[qi] = W2r[qi * 2 + 1];
            }
            const float bb0 = b2[0], bb1 = b2[1];

            const float4* Drow = (const float4*)(Dd + ((b * N1 + i + 1) << 8)) + t * 4;
            float* Sout = S + b * NTRI + base + i * nj;

            for (int jp = 0; jp < nj; ++jp) {
                float s0 = 0.f, s1 = 0.f;
                #pragma unroll
                for (int qi = 0; qi < 4; ++qi) {
                    float4 dd = Drow[qi];
                    float r0 = fmaxf(dd.x + qq[qi].x - pp[qi].x, 0.f);
                    float r1 = fmaxf(dd.y + qq[qi].y - pp[qi].y, 0.f);
                    float r2 = fmaxf(dd.z + qq[qi].z - pp[qi].z, 0.f);
                    float r3 = fmaxf(dd.w + qq[qi].w - pp[qi].w, 0.f);
                    s0 = fmaf(r0, wa[qi].x, s0); s1 = fmaf(r0, wa[qi].y, s1);
                    s0 = fmaf(r1, wa[qi].z, s0); s1 = fmaf(r1, wa[qi].w, s1);
                    s0 = fmaf(r2, wb[qi].x, s0); s1 = fmaf(r2, wb[qi].y, s1);
                    s0 = fmaf(r3, wb[qi].z, s0); s1 = fmaf(r3, wb[qi].w, s1);
                }
                #pragma unroll
                for (int d = 1; d < 16; d <<= 1) {
                    s0 += __shfl_xor(s0, d);
                    s1 += __shfl_xor(s1, d);
                }
                if (t == 0) {
                    float S0 = s0 + bb0, S1 = s1 + bb1;
                    Sout[jp] = fmaxf(S0, S1) + log1pf(__expf(-fabsf(S0 - S1)));
                }
                Drow += 64;
            }
        }

        // ---- arrive score counter (12 per line, 8 lines) and exit
        __syncthreads();
        if (tid == 0) {
            __threadfence();
            __hip_atomic_fetch_add(&g_sync[b][64], 1ull, __ATOMIC_RELEASE,
                                   __HIP_MEMORY_SCOPE_AGENT);
        }
        return;
    }

    // ======== block 12: wait for this batch's 12 score arrivals
    if (tid == 0) {
        while (__hip_atomic_load(&g_sync[b][64], __ATOMIC_RELAXED,
                                 __HIP_MEMORY_SCOPE_AGENT) < (unsigned long long)SCB)
            __builtin_amdgcn_s_sleep(16);
        __threadfence();
    }
    __syncthreads();

    // ======== phase 3: DP for batch b (verbatim; threads >=256 excluded by
    // tid < m*T inside dp_step, all 16 waves join the barriers)
    {
        const float4* src = (const float4*)(S + b * NTRI);
        float4* dst = (float4*)sh.dp.Sl;
        for (int x = tid; x < NTRI / 4; x += THR) dst[x] = src[x];
        if (tid < N_TOK) sh.dp.Btri[tri_base(tid)] = 0.f;
        __syncthreads();

        dp_from<2>(sh.dp.Btri, sh.dp.Sl, tid);

        if (tid == 0) {
            int L = lengths[b];
            out[b] = sh.dp.Btri[BIDX(0, L)];
        }
    }

    // ---- reset this group's counters (we are their last user this launch)
    if (tid == 0) {
        __hip_atomic_store(&g_sync[b][0], 0ull, __ATOMIC_RELAXED,
                           __HIP_MEMORY_SCOPE_AGENT);
        __hip_atomic_store(&g_sync[b][64], 0ull, __ATOMIC_RELAXED,
                           __HIP_MEMORY_SCOPE_AGENT);
    }
}

extern "C" void kernel_launch(void* const* d_in, const int* in_sizes, int n_in,
                              void* d_out, int out_size, void* d_ws, size_t ws_size,
                              hipStream_t stream)
{
    const float* enc = (const float*)d_in[0];
    const float* W1  = (const float*)d_in[1];
    const float* b1  = (const float*)d_in[2];
    const float* W2  = (const float*)d_in[3];
    const float* b2  = (const float*)d_in[4];
    const int* lengths = (const int*)d_in[5];

    float* ws = (float*)d_ws;
    float* P  = ws;
    float* Qb = ws + ROWF;
    float* Dd = ws + 2 * ROWF;
    float* S  = ws + 3 * ROWF;

    k_fused<<<dim3(NBF), dim3(THR), 0, stream>>>(
        enc, W1, b1, W2, b2, lengths, P, Qb, Dd, S, (float*)d_out);
}